// Round 1
// baseline (8159.238 us; speedup 1.0000x reference)
//
#include <hip/hip_runtime.h>
#include <hip/hip_bf16.h>
#include <math.h>

// Problem dims
#define BATCH 32
#define SEQ   500
#define NQ    3000
#define EMB   256
#define HID   256
#define ROWS  (BATCH * SEQ)        // 16000
#define X_K   (2 * NQ)             // 6000

// ---------------- Generic tiled fp32 GEMM ----------------
// C[M,N] = A[M,K] @ B (+bias).  TRANSB=false: B is [K,N]; TRANSB=true: B is [N,K].
// Supports batched launches via blockIdx.z strides and a C leading dimension.
#define BM 64
#define BN 64
#define BK 16

template<bool TRANSB, bool HASBIAS>
__global__ __launch_bounds__(256)
void gemm_kernel(const float* __restrict__ A, const float* __restrict__ B,
                 const float* __restrict__ bias, float* __restrict__ C,
                 int M, int N, int K, int ldc,
                 long long sA, long long sB, long long sC)
{
    A += (long long)blockIdx.z * sA;
    B += (long long)blockIdx.z * sB;
    C += (long long)blockIdx.z * sC;

    __shared__ __align__(16) float As[BK][BM + 4];
    __shared__ __align__(16) float Bs[BK][BN + 4];

    const int tid = threadIdx.x;
    const int tx  = tid & 15;      // column group (n)
    const int ty  = tid >> 4;      // row group (m)
    const int m0  = blockIdx.y * BM;
    const int n0  = blockIdx.x * BN;

    float acc[4][4] = {};

    const int arow = tid >> 2;          // 0..63
    const int akg  = (tid & 3) * 4;     // 0,4,8,12

    const int ktiles = (K + BK - 1) / BK;
    for (int kt = 0; kt < ktiles; ++kt) {
        const int k0 = kt * BK;
        // ---- load A tile (BM x BK), store transposed As[k][m]
        {
            const int gm = m0 + arow;
            const int gk = k0 + akg;
            float4 v = make_float4(0.f, 0.f, 0.f, 0.f);
            if (gm < M) {
                const float* p = A + (long long)gm * K;
                if (gk + 3 < K) {
                    v = *reinterpret_cast<const float4*>(p + gk);
                } else {
                    if (gk + 0 < K) v.x = p[gk + 0];
                    if (gk + 1 < K) v.y = p[gk + 1];
                    if (gk + 2 < K) v.z = p[gk + 2];
                    if (gk + 3 < K) v.w = p[gk + 3];
                }
            }
            As[akg + 0][arow] = v.x;
            As[akg + 1][arow] = v.y;
            As[akg + 2][arow] = v.z;
            As[akg + 3][arow] = v.w;
        }
        // ---- load B tile (BK x BN), store Bs[k][n]
        if (!TRANSB) {
            const int gk = k0 + (tid >> 4);
            const int gn = n0 + (tid & 15) * 4;
            float4 v = make_float4(0.f, 0.f, 0.f, 0.f);
            if (gk < K) {
                const float* p = B + (long long)gk * N;
                if (gn + 3 < N) {
                    v = *reinterpret_cast<const float4*>(p + gn);
                } else {
                    if (gn + 0 < N) v.x = p[gn + 0];
                    if (gn + 1 < N) v.y = p[gn + 1];
                    if (gn + 2 < N) v.z = p[gn + 2];
                    if (gn + 3 < N) v.w = p[gn + 3];
                }
            }
            const int r = tid >> 4, c = (tid & 15) * 4;
            Bs[r][c + 0] = v.x; Bs[r][c + 1] = v.y;
            Bs[r][c + 2] = v.z; Bs[r][c + 3] = v.w;
        } else {
            const int gn = n0 + (tid >> 2);
            const int gk = k0 + (tid & 3) * 4;
            float4 v = make_float4(0.f, 0.f, 0.f, 0.f);
            if (gn < N) {
                const float* p = B + (long long)gn * K;
                if (gk + 3 < K) {
                    v = *reinterpret_cast<const float4*>(p + gk);
                } else {
                    if (gk + 0 < K) v.x = p[gk + 0];
                    if (gk + 1 < K) v.y = p[gk + 1];
                    if (gk + 2 < K) v.z = p[gk + 2];
                    if (gk + 3 < K) v.w = p[gk + 3];
                }
            }
            const int n = tid >> 2, kk = (tid & 3) * 4;
            Bs[kk + 0][n] = v.x; Bs[kk + 1][n] = v.y;
            Bs[kk + 2][n] = v.z; Bs[kk + 3][n] = v.w;
        }
        __syncthreads();

        #pragma unroll
        for (int kk = 0; kk < BK; ++kk) {
            const float4 a = *reinterpret_cast<const float4*>(&As[kk][ty * 4]);
            const float4 b = *reinterpret_cast<const float4*>(&Bs[kk][tx * 4]);
            acc[0][0] = fmaf(a.x, b.x, acc[0][0]); acc[0][1] = fmaf(a.x, b.y, acc[0][1]);
            acc[0][2] = fmaf(a.x, b.z, acc[0][2]); acc[0][3] = fmaf(a.x, b.w, acc[0][3]);
            acc[1][0] = fmaf(a.y, b.x, acc[1][0]); acc[1][1] = fmaf(a.y, b.y, acc[1][1]);
            acc[1][2] = fmaf(a.y, b.z, acc[1][2]); acc[1][3] = fmaf(a.y, b.w, acc[1][3]);
            acc[2][0] = fmaf(a.z, b.x, acc[2][0]); acc[2][1] = fmaf(a.z, b.y, acc[2][1]);
            acc[2][2] = fmaf(a.z, b.z, acc[2][2]); acc[2][3] = fmaf(a.z, b.w, acc[2][3]);
            acc[3][0] = fmaf(a.w, b.x, acc[3][0]); acc[3][1] = fmaf(a.w, b.y, acc[3][1]);
            acc[3][2] = fmaf(a.w, b.z, acc[3][2]); acc[3][3] = fmaf(a.w, b.w, acc[3][3]);
        }
        __syncthreads();
    }

    #pragma unroll
    for (int i = 0; i < 4; ++i) {
        const int gm = m0 + ty * 4 + i;
        if (gm >= M) continue;
        #pragma unroll
        for (int j = 0; j < 4; ++j) {
            const int gn = n0 + tx * 4 + j;
            if (gn >= N) continue;
            float v = acc[i][j];
            if (HASBIAS) v += bias[gn];
            C[(long long)gm * ldc + gn] = v;
        }
    }
}

// ---------------- small transpose: [768,256] -> [256,768] ----------------
__global__ __launch_bounds__(256)
void transpose_kernel(const float* __restrict__ in, float* __restrict__ out)
{
    const int idx = blockIdx.x * 256 + threadIdx.x;  // grid 768 -> 196608
    const int d = idx >> 8;     // 0..767
    const int k = idx & 255;    // 0..255
    out[k * 768 + d] = in[idx];
}

// ---------------- GRU: one block per (gru, batch) ----------------
// xp: [32][500][768] precomputed x-projections (bias included)
// wT: [256][768]  transposed w_hh   bh: [768]   out: [32][500][256]
__global__ __launch_bounds__(256)
void gru_kernel(const float* __restrict__ xp1, const float* __restrict__ xp2,
                const float* __restrict__ wT1, const float* __restrict__ wT2,
                const float* __restrict__ bh1, const float* __restrict__ bh2,
                float* __restrict__ out1, float* __restrict__ out2)
{
    const int g = blockIdx.x >> 5;
    const int b = blockIdx.x & 31;
    const float* xp = (g ? xp2 : xp1) + (long long)b * SEQ * 768;
    const float* wT = g ? wT2 : wT1;
    const float* bh = g ? bh2 : bh1;
    float* out      = (g ? out2 : out1) + (long long)b * SEQ * HID;

    __shared__ float h[HID];
    const int j = threadIdx.x;
    h[j] = 0.f;
    const float br = bh[j], bz = bh[HID + j], bn = bh[2 * HID + j];
    __syncthreads();

    for (int t = 0; t < SEQ; ++t) {
        const float* xrow = xp + (long long)t * 768;
        float ar = br, az = bz, an = bn;
        #pragma unroll 8
        for (int k = 0; k < HID; ++k) {
            const float hk = h[k];
            const float* wrow = wT + k * 768;
            ar = fmaf(hk, wrow[j], ar);
            az = fmaf(hk, wrow[HID + j], az);
            an = fmaf(hk, wrow[2 * HID + j], an);
        }
        const float r = 1.f / (1.f + __expf(-(xrow[j] + ar)));
        const float z = 1.f / (1.f + __expf(-(xrow[HID + j] + az)));
        const float n = tanhf(xrow[2 * HID + j] + r * an);
        const float hnew = (1.f - z) * n + z * h[j];
        out[(long long)t * HID + j] = hnew;
        __syncthreads();   // all reads of h done
        h[j] = hnew;
        __syncthreads();   // writes visible before next step
    }
}

// ---------------- softmax over rows of length 500 (in place) ----------------
__global__ __launch_bounds__(256)
void softmax_kernel(float* __restrict__ s)
{
    float* p = s + (long long)blockIdx.x * SEQ;
    const int tid = threadIdx.x;
    __shared__ float red[256];

    const float v0 = (tid < SEQ) ? p[tid] : -1e30f;
    const float v1 = (tid + 256 < SEQ) ? p[tid + 256] : -1e30f;
    red[tid] = fmaxf(v0, v1);
    __syncthreads();
    for (int o = 128; o > 0; o >>= 1) {
        if (tid < o) red[tid] = fmaxf(red[tid], red[tid + o]);
        __syncthreads();
    }
    const float m = red[0];
    __syncthreads();
    const float e0 = (tid < SEQ) ? __expf(v0 - m) : 0.f;
    const float e1 = (tid + 256 < SEQ) ? __expf(v1 - m) : 0.f;
    red[tid] = e0 + e1;
    __syncthreads();
    for (int o = 128; o > 0; o >>= 1) {
        if (tid < o) red[tid] += red[tid + o];
        __syncthreads();
    }
    const float inv = 1.f / red[0];
    if (tid < SEQ) p[tid] = e0 * inv;
    if (tid + 256 < SEQ) p[tid + 256] = e1 * inv;
}

// ---------------- column sum: [32][500][256] -> [32][256] ----------------
__global__ __launch_bounds__(256)
void colsum_kernel(const float* __restrict__ x, float* __restrict__ out)
{
    const int b = blockIdx.x, hh = threadIdx.x;
    const float* p = x + (long long)b * SEQ * HID + hh;
    float s = 0.f;
    for (int t = 0; t < SEQ; ++t) s += p[t * HID];
    out[b * HID + hh] = s;
}

// ---------------- fused_h combine: ens[...,256+h] = colsum - tmp ----------------
__global__ __launch_bounds__(256)
void combine_kernel(const float* __restrict__ tmp, const float* __restrict__ cs,
                    float* __restrict__ ens)
{
    const long long r = blockIdx.x;      // 0..15999 = b*500+s
    const int hh = threadIdx.x;
    const int b = (int)(r / SEQ);
    ens[r * 512 + 256 + hh] = cs[b * HID + hh] - tmp[r * HID + hh];
}

// ---------------- launch ----------------
extern "C" void kernel_launch(void* const* d_in, const int* in_sizes, int n_in,
                              void* d_out, int out_size, void* d_ws, size_t ws_size,
                              hipStream_t stream)
{
    const float* x      = (const float*)d_in[0];
    const float* ques_h = (const float*)d_in[1];
    const float* ques_d = (const float*)d_in[2];
    const float* w1ih   = (const float*)d_in[3];
    const float* w1hh   = (const float*)d_in[4];
    const float* b1ih   = (const float*)d_in[5];
    const float* b1hh   = (const float*)d_in[6];
    const float* w2ih   = (const float*)d_in[7];
    const float* w2hh   = (const float*)d_in[8];
    const float* b2ih   = (const float*)d_in[9];
    const float* b2hh   = (const float*)d_in[10];
    const float* fcc_w  = (const float*)d_in[11];
    const float* fcc_b  = (const float*)d_in[12];
    const float* fct_w  = (const float*)d_in[13];
    const float* fct_b  = (const float*)d_in[14];
    const float* fce_w  = (const float*)d_in[15];
    const float* fce_b  = (const float*)d_in[16];

    float* ws = (float*)d_ws;
    // workspace layout (floats)
    float* xh    = ws;                         //  4,096,000
    float* xd    = ws + 4096000LL;             //  4,096,000
    float* xp1   = ws + 8192000LL;             // 12,288,000
    float* xp2   = ws + 20480000LL;            // 12,288,000
    float* outh  = ws + 32768000LL;            //  4,096,000
    float* outd  = ws + 36864000LL;            //  4,096,000
    float* wT1   = ws + 40960000LL;            //    196,608
    float* wT2   = ws + 41156608LL;            //    196,608
    float* cs    = ws + 41353216LL;            //      8,192
    // aliases of dead regions:
    float* attn  = xp1;                        // 8,000,000  (32*500*500), xp1 dead after GRU
    float* ens   = xp2;                        // 8,192,000  (32*500*512), xp2 dead after GRU
    float* tmp   = ws + 28672000LL;            // 4,096,000  tail of xp2 region

    float* out_c = (float*)d_out;              // [16000,3000]
    float* out_t = out_c + 48000000LL;
    float* out_e = out_c + 96000000LL;

    const dim3 blk(256);

    // 1) embeddings: xh = x@ques_h, xd = x@ques_d   [16000,6000]x[6000,256]
    gemm_kernel<false, false><<<dim3(4, 250, 1), blk, 0, stream>>>(
        x, ques_h, nullptr, xh, ROWS, EMB, X_K, EMB, 0, 0, 0);
    gemm_kernel<false, false><<<dim3(4, 250, 1), blk, 0, stream>>>(
        x, ques_d, nullptr, xd, ROWS, EMB, X_K, EMB, 0, 0, 0);

    // 2) input projections: xp = xemb @ w_ih^T + b_ih   [16000,256]x[768,256]^T
    gemm_kernel<true, true><<<dim3(12, 250, 1), blk, 0, stream>>>(
        xh, w1ih, b1ih, xp1, ROWS, 768, EMB, 768, 0, 0, 0);
    gemm_kernel<true, true><<<dim3(12, 250, 1), blk, 0, stream>>>(
        xd, w2ih, b2ih, xp2, ROWS, 768, EMB, 768, 0, 0, 0);

    // 3) transpose recurrent weights for coalesced access
    transpose_kernel<<<768, blk, 0, stream>>>(w1hh, wT1);
    transpose_kernel<<<768, blk, 0, stream>>>(w2hh, wT2);

    // 4) dual GRU, one block per (gru,batch)
    gru_kernel<<<64, blk, 0, stream>>>(xp1, xp2, wT1, wT2, b1hh, b2hh, outh, outd);

    // 5) per-branch logits
    gemm_kernel<true, true><<<dim3(47, 250, 1), blk, 0, stream>>>(
        outh, fcc_w, fcc_b, out_c, ROWS, NQ, HID, NQ, 0, 0, 0);
    gemm_kernel<true, true><<<dim3(47, 250, 1), blk, 0, stream>>>(
        outd, fct_w, fct_b, out_t, ROWS, NQ, HID, NQ, 0, 0, 0);

    // 6) attention scores: scores[b] = outh[b] @ outd[b]^T   [500,256]x[500,256]^T
    gemm_kernel<true, false><<<dim3(8, 8, 32), blk, 0, stream>>>(
        outh, outd, nullptr, attn, SEQ, SEQ, HID, SEQ,
        (long long)SEQ * HID, (long long)SEQ * HID, (long long)SEQ * SEQ);

    // 7) softmax rows (in place)
    softmax_kernel<<<ROWS, blk, 0, stream>>>(attn);

    // 8) colsum of outh per batch (for 1-attn trick)
    colsum_kernel<<<32, blk, 0, stream>>>(outh, cs);

    // 9) fused_d = attn @ outd -> ens[:, 0:256];  tmp = attn @ outh
    gemm_kernel<false, false><<<dim3(4, 8, 32), blk, 0, stream>>>(
        attn, outd, nullptr, ens, SEQ, HID, SEQ, 512,
        (long long)SEQ * SEQ, (long long)SEQ * HID, (long long)SEQ * 512);
    gemm_kernel<false, false><<<dim3(4, 8, 32), blk, 0, stream>>>(
        attn, outh, nullptr, tmp, SEQ, HID, SEQ, HID,
        (long long)SEQ * SEQ, (long long)SEQ * HID, (long long)SEQ * HID);

    // 10) ens[:, 256:512] = colsum - tmp
    combine_kernel<<<ROWS, blk, 0, stream>>>(tmp, cs, ens);

    // 11) ensemble logits: out_e = ens @ fce_w^T + fce_b   [16000,512]x[3000,512]^T
    gemm_kernel<true, true><<<dim3(47, 250, 1), blk, 0, stream>>>(
        ens, fce_w, fce_b, out_e, ROWS, NQ, 512, NQ, 0, 0, 0);
}